// Round 5
// baseline (88272.021 us; speedup 1.0000x reference)
//
#include <hip/hip_runtime.h>
#include <math.h>

#define Bx 64
#define Tx 800
#define Ux 80
#define INx 3
#define Hx 400
#define Vx 57
#define Kx 10
#define TT 50      // steps per xg chunk
#define NC 16      // chunks per layer

// Activation layouts (b fastest):
//  out0/out12 : t*25600 + h*64 + b
//  win        : t*3648  + v*64 + b
//  abk        : t*1920  + j*64 + b
//  xT         : t*192   + d*64 + b
//  ohT        : (u*57+v)*64 + b
//  xg chunk   : tt*76800 + row*64 + b        (row = gate row 0..1199, incl b_ih)
//  Wpk        : v2f index j*1200 + row ; value = (Whh[row][2j], Whh[row][2j+1])
//
// k_rec: SYNC-FREE persistent recurrence. 16 WGs x 640 thr; WG = 4 chains
// (cb = 4*blockIdx). Each WG computes ALL 1200 gate rows per step -> no
// cross-WG exchange, no fences, no atomics. h ping-pongs in LDS (broadcast
// reads). Weights streamed from L2 (1.92 MB/step/WG; 2 WGs/XCD share it).

typedef float v2f __attribute__((ext_vector_type(2)));
typedef float v4f __attribute__((ext_vector_type(4)));

__device__ __forceinline__ float sigf(float x) { return 1.f / (1.f + expf(-x)); }

// acc.xy += w.x * h.xy   (broadcast LOW half of S0)  [verified R2/R4]
__device__ __forceinline__ void pk_lo(v2f& acc, v2f w, v2f h) {
    asm("v_pk_fma_f32 %0, %1, %2, %0 op_sel:[0,0,0] op_sel_hi:[0,1,1]"
        : "+v"(acc) : "v"(w), "v"(h));
}
// acc.xy += w.y * h.xy   (broadcast HIGH half of S0)
__device__ __forceinline__ void pk_hi(v2f& acc, v2f w, v2f h) {
    asm("v_pk_fma_f32 %0, %1, %2, %0 op_sel:[1,0,0] op_sel_hi:[1,1,1]"
        : "+v"(acc) : "v"(w), "v"(h));
}

__global__ void k_transpose_x(const float* __restrict__ x, float* __restrict__ xT) {
    int idx = blockIdx.x * blockDim.x + threadIdx.x;
    if (idx >= Tx * INx * Bx) return;
    int b = idx & 63;
    int d = (idx >> 6) % INx;
    int t = idx / (64 * INx);
    xT[idx] = x[((size_t)b * Tx + t) * INx + d];
}

__global__ void k_transpose_oh(const float* __restrict__ oh, float* __restrict__ ohT) {
    int idx = blockIdx.x * blockDim.x + threadIdx.x;
    if (idx >= Ux * Vx * Bx) return;
    int b = idx & 63;
    int uv = idx >> 6;
    int v = uv % Vx;
    int u = uv / Vx;
    ohT[idx] = oh[((size_t)b * Ux + u) * Vx + v];
}

// Wpk[j*1200 + r] = (Whh[r][2j], Whh[r][2j+1]),  j in [0,200), r in [0,1200)
__global__ void k_packW(const float* __restrict__ Whh, float* __restrict__ Wpk) {
    int idx = blockIdx.x * blockDim.x + threadIdx.x;
    if (idx >= 200 * 1200) return;
    int j = idx / 1200;
    int r = idx % 1200;
    Wpk[(size_t)idx * 2]     = Whh[(size_t)r * 400 + 2 * j];
    Wpk[(size_t)idx * 2 + 1] = Whh[(size_t)r * 400 + 2 * j + 1];
}

// Sync-free GRU recurrence. L0=1: layer 0 (x-side inline, 3 cols);
// L0=0: layers 1/2 (x-side from xg chunk, includes b_ih).
template <int L0>
__global__ __launch_bounds__(640, 1) void k_rec(
    const float* __restrict__ Wpk, const float* __restrict__ xg,
    const float* __restrict__ xT, const float* __restrict__ hinit,
    const float* __restrict__ Wih0, const float* __restrict__ bih,
    const float* __restrict__ bhh, float* __restrict__ outL,
    int t0, int nt) {
    __shared__ __align__(16) float hbuf[2][400 * 4];   // [k][c] ping-pong
    __shared__ __align__(16) float gates[1200 * 4];    // [row][c] raw Whh dots

    const int tid = threadIdx.x;
    const int cb = blockIdx.x * 4;
    const int r0 = tid;          // rows r0, r0+600 (tid < 600)
    const int r1 = tid + 600;

    // per-thread activation constants (tid < 400 = unit u)
    float bhr = 0, bhz = 0, bhn = 0;
    float bir = 0, biz = 0, bin_ = 0;
    float wx[9];
    if (tid < 400) {
        bhr = bhh[tid]; bhz = bhh[400 + tid]; bhn = bhh[800 + tid];
        if (L0) {
            bir = bih[tid]; biz = bih[400 + tid]; bin_ = bih[800 + tid];
            #pragma unroll
            for (int d = 0; d < 3; ++d) {
                wx[d]     = Wih0[(size_t)tid * 3 + d];
                wx[3 + d] = Wih0[(size_t)(400 + tid) * 3 + d];
                wx[6 + d] = Wih0[(size_t)(800 + tid) * 3 + d];
            }
        }
    }

    // stage h(t0-1)
    if (tid < 400) {
        v4f hv;
        if (t0 == 0) {
            hv.x = hinit[(size_t)(cb + 0) * 400 + tid];
            hv.y = hinit[(size_t)(cb + 1) * 400 + tid];
            hv.z = hinit[(size_t)(cb + 2) * 400 + tid];
            hv.w = hinit[(size_t)(cb + 3) * 400 + tid];
        } else {
            hv = *(const v4f*)(outL + (size_t)(t0 - 1) * 25600 + tid * 64 + cb);
        }
        *(v4f*)&hbuf[0][tid * 4] = hv;
    }
    __syncthreads();

    const v2f* Wp2 = (const v2f*)Wpk;

    for (int tt = 0; tt < nt; ++tt) {
        const int t = t0 + tt;
        const int p = tt & 1;

        // ---- dot phase: rows r0, r1 over full k (tid < 600)
        if (tid < 600) {
            v2f a001 = {0, 0}, a023 = {0, 0}, a101 = {0, 0}, a123 = {0, 0};
            const v4f* hp = (const v4f*)&hbuf[p][0];
            const v2f* w0p = Wp2 + r0;
            const v2f* w1p = Wp2 + r1;
            #pragma unroll 4
            for (int j = 0; j < 200; ++j) {
                v2f w0 = w0p[0];
                v2f w1 = w1p[0];
                v4f hA = hp[2 * j];       // k=2j   : chains (x,y)=(0,1) (z,w)=(2,3)
                v4f hB = hp[2 * j + 1];   // k=2j+1
                pk_lo(a001, w0, hA.xy);  pk_hi(a001, w0, hB.xy);
                pk_lo(a023, w0, hA.zw);  pk_hi(a023, w0, hB.zw);
                pk_lo(a101, w1, hA.xy);  pk_hi(a101, w1, hB.xy);
                pk_lo(a123, w1, hA.zw);  pk_hi(a123, w1, hB.zw);
                w0p += 1200;
                w1p += 1200;
            }
            *(v2f*)&gates[r0 * 4]     = a001;
            *(v2f*)&gates[r0 * 4 + 2] = a023;
            *(v2f*)&gates[r1 * 4]     = a101;
            *(v2f*)&gates[r1 * 4 + 2] = a123;
        }
        __syncthreads();

        // ---- activation phase (tid < 400 = unit u)
        if (tid < 400) {
            int u = tid;
            v4f R  = *(const v4f*)&gates[u * 4];
            v4f Z  = *(const v4f*)&gates[(400 + u) * 4];
            v4f HN = *(const v4f*)&gates[(800 + u) * 4];
            v4f XR, XZ, XN;
            if (L0) {
                v4f x0 = *(const v4f*)(xT + (size_t)t * 192 + 0 * 64 + cb);
                v4f x1 = *(const v4f*)(xT + (size_t)t * 192 + 1 * 64 + cb);
                v4f x2 = *(const v4f*)(xT + (size_t)t * 192 + 2 * 64 + cb);
                XR = bir  + wx[0] * x0 + wx[1] * x1 + wx[2] * x2;
                XZ = biz  + wx[3] * x0 + wx[4] * x1 + wx[5] * x2;
                XN = bin_ + wx[6] * x0 + wx[7] * x1 + wx[8] * x2;
            } else {
                const float* xb = xg + (size_t)tt * 76800;
                XR = *(const v4f*)(xb + (size_t)u * 64 + cb);
                XZ = *(const v4f*)(xb + (size_t)(400 + u) * 64 + cb);
                XN = *(const v4f*)(xb + (size_t)(800 + u) * 64 + cb);
            }
            v4f hp4 = *(const v4f*)&hbuf[p][u * 4];
            v4f hn4;
            #pragma unroll
            for (int c = 0; c < 4; ++c) {
                float r = sigf(XR[c] + R[c] + bhr);
                float z = sigf(XZ[c] + Z[c] + bhz);
                float n = tanhf(XN[c] + r * (HN[c] + bhn));
                hn4[c] = (1.f - z) * n + z * hp4[c];
            }
            *(v4f*)&hbuf[p ^ 1][u * 4] = hn4;
            *(v4f*)(outL + (size_t)t * 25600 + u * 64 + cb) = hn4;
        }
        __syncthreads();
    }
}

// abk = exp(out0 @ W_win^T + b_win), parallel over t. grid 800 x 256.
__global__ __launch_bounds__(256) void k_abk(const float* __restrict__ out0,
    const float* __restrict__ Wwin, const float* __restrict__ bwin,
    float* __restrict__ abk) {
    int t = blockIdx.x;
    int b = threadIdx.x & 63;
    int js = threadIdx.x >> 6;
    int j0 = js * 8;
    int nj = min(8, 30 - j0);
    float acc[8];
    for (int i = 0; i < nj; i++) acc[i] = bwin[j0 + i];
    const float* o = out0 + (size_t)t * 25600;
    for (int k = 0; k < Hx; k++) {
        float hv = o[k * 64 + b];
        for (int i = 0; i < nj; i++) acc[i] += Wwin[(j0 + i) * Hx + k] * hv;
    }
    for (int i = 0; i < nj; i++)
        abk[(size_t)t * 1920 + (j0 + i) * 64 + b] = expf(acc[i]);
}

__global__ void k_cumsum(float* __restrict__ abk) {
    int tid = blockIdx.x * blockDim.x + threadIdx.x;
    if (tid >= Kx * Bx) return;
    int b = tid & 63;
    int k = tid >> 6;
    float run = 0.f;
    size_t base = (size_t)(20 + k) * 64 + b;
    for (int t = 0; t < Tx; t++) {
        size_t i = (size_t)t * 1920 + base;
        run += abk[i];
        abk[i] = run;
    }
}

__global__ __launch_bounds__(256) void k_window(const float* __restrict__ abk,
    const float* __restrict__ ohT, float* __restrict__ win) {
    int t = blockIdx.x;
    int b = threadIdx.x & 63;
    int sub = threadIdx.x >> 6;
    __shared__ float phi[Ux][64];

    float al[Kx], be[Kx], kc[Kx];
    const float* ab = abk + (size_t)t * 1920;
    #pragma unroll
    for (int k = 0; k < Kx; k++) {
        al[k] = ab[k * 64 + b];
        be[k] = ab[(10 + k) * 64 + b];
        kc[k] = ab[(20 + k) * 64 + b];
    }
    for (int u = sub * 20; u < sub * 20 + 20; u++) {
        float ssum = 0.f;
        float uf = (float)u;
        #pragma unroll
        for (int k = 0; k < Kx; k++) {
            float d = kc[k] - uf;
            ssum += al[k] * __expf(-be[k] * d * d);
        }
        phi[u][b] = ssum;
    }
    __syncthreads();

    int v0 = sub * 15;
    int nv = min(15, Vx - v0);
    float acc[15];
    for (int i = 0; i < nv; i++) acc[i] = 0.f;
    for (int u = 0; u < Ux; u++) {
        float pv = phi[u][b];
        const float* oh = ohT + (size_t)(u * Vx) * 64;
        for (int i = 0; i < nv; i++) acc[i] += pv * oh[(v0 + i) * 64 + b];
    }
    for (int i = 0; i < nv; i++)
        win[(size_t)t * 3648 + (v0 + i) * 64 + b] = acc[i];
}

// Input-side projection for layers 1/2, one TT-step chunk.
// grid (TT, 75), block 256: 16 gate rows per block-y tile, 4 per thread.
__global__ __launch_bounds__(256) void k_xg(const float* __restrict__ outprev,
    const float* __restrict__ win, const float* __restrict__ xT,
    const float* __restrict__ Wih, const float* __restrict__ bih,
    float* __restrict__ xg, int t0) {
    int tt = blockIdx.x;
    int gt = blockIdx.y;
    int t = t0 + tt;
    int b = threadIdx.x & 63;
    int du = threadIdx.x >> 6;
    int g = gt * 16 + du * 4;

    float a0 = bih[g], a1 = bih[g + 1], a2 = bih[g + 2], a3 = bih[g + 3];
    const float* w0 = Wih + (size_t)g * 460;
    const float* w1 = w0 + 460;
    const float* w2 = w0 + 920;
    const float* w3 = w0 + 1380;

    const float* op = outprev + (size_t)t * 25600;
    for (int d = 0; d < 400; d += 4) {
        float4 q0 = *(const float4*)(w0 + d);
        float4 q1 = *(const float4*)(w1 + d);
        float4 q2 = *(const float4*)(w2 + d);
        float4 q3 = *(const float4*)(w3 + d);
        float i0 = op[d * 64 + b];
        float i1 = op[(d + 1) * 64 + b];
        float i2 = op[(d + 2) * 64 + b];
        float i3 = op[(d + 3) * 64 + b];
        a0 += q0.x * i0 + q0.y * i1 + q0.z * i2 + q0.w * i3;
        a1 += q1.x * i0 + q1.y * i1 + q1.z * i2 + q1.w * i3;
        a2 += q2.x * i0 + q2.y * i1 + q2.z * i2 + q2.w * i3;
        a3 += q3.x * i0 + q3.y * i1 + q3.z * i2 + q3.w * i3;
    }
    const float* wp = win + (size_t)t * 3648;
    for (int d = 0; d < Vx; d++) {
        float iv = wp[d * 64 + b];
        a0 += w0[400 + d] * iv;
        a1 += w1[400 + d] * iv;
        a2 += w2[400 + d] * iv;
        a3 += w3[400 + d] * iv;
    }
    const float* xp = xT + (size_t)t * 192;
    #pragma unroll
    for (int d = 0; d < 3; d++) {
        float iv = xp[d * 64 + b];
        a0 += w0[457 + d] * iv;
        a1 += w1[457 + d] * iv;
        a2 += w2[457 + d] * iv;
        a3 += w3[457 + d] * iv;
    }
    size_t o = (size_t)tt * 76800 + (size_t)g * 64 + b;
    xg[o] = a0;
    xg[o + 64] = a1;
    xg[o + 128] = a2;
    xg[o + 192] = a3;
}

// MDN head: out[(b*T+t)*121 + j], tanh on j in [100,120). grid 800 x 256.
__global__ __launch_bounds__(256) void k_mdn(const float* __restrict__ out2,
    const float* __restrict__ Wm, const float* __restrict__ bm,
    float* __restrict__ out) {
    int t = blockIdx.x;
    int b = threadIdx.x & 63;
    int js = threadIdx.x >> 6;
    int j0 = js * 31;
    int nj = min(31, 121 - j0);
    float acc[31];
    for (int i = 0; i < nj; i++) acc[i] = bm[j0 + i];
    const float* o = out2 + (size_t)t * 25600;
    for (int k = 0; k < Hx; k += 4) {
        float i0 = o[k * 64 + b];
        float i1 = o[(k + 1) * 64 + b];
        float i2 = o[(k + 2) * 64 + b];
        float i3 = o[(k + 3) * 64 + b];
        for (int i = 0; i < nj; i++) {
            const float* wp = Wm + (size_t)(j0 + i) * Hx + k;
            float4 qv = *(const float4*)wp;
            acc[i] += qv.x * i0 + qv.y * i1 + qv.z * i2 + qv.w * i3;
        }
    }
    size_t rb = ((size_t)b * Tx + t) * 121;
    for (int i = 0; i < nj; i++) {
        int j = j0 + i;
        float v = acc[i];
        if (j >= 100 && j < 120) v = tanhf(v);
        out[rb + j] = v;
    }
}

extern "C" void kernel_launch(void* const* d_in, const int* in_sizes, int n_in,
                              void* d_out, int out_size, void* d_ws, size_t ws_size,
                              hipStream_t stream) {
    const float* x    = (const float*)d_in[0];
    const float* oneh = (const float*)d_in[1];
    const float* h0i  = (const float*)d_in[2];
    const float* h1i  = (const float*)d_in[3];
    const float* h2i  = (const float*)d_in[4];
    const float* Wih0 = (const float*)d_in[5];
    const float* Whh0 = (const float*)d_in[6];
    const float* bih0 = (const float*)d_in[7];
    const float* bhh0 = (const float*)d_in[8];
    const float* Wih1 = (const float*)d_in[9];
    const float* Whh1 = (const float*)d_in[10];
    const float* bih1 = (const float*)d_in[11];
    const float* bhh1 = (const float*)d_in[12];
    const float* Wwin = (const float*)d_in[13];
    const float* bwin = (const float*)d_in[14];
    const float* Wmdn = (const float*)d_in[15];
    const float* bmdn = (const float*)d_in[16];

    float* ws    = (float*)d_ws;
    float* out0  = ws;                    // 20,480,000
    float* out12 = ws + 20480000;         // 20,480,000
    float* winb  = ws + 40960000;         //  2,918,400
    float* abk   = ws + 43878400;         //  1,536,000
    float* xg    = ws + 45414400;         //  3,840,000 (TT=50 chunk)
    float* xT    = ws + 49254400;         //    153,600
    float* ohT   = ws + 49408000;         //    291,840
    float* Wpk0  = ws + 49699840;         //    480,000
    float* Wpk12 = ws + 50179840;         //    480,000
    // total 50,659,840 floats = 202.6 MB

    hipLaunchKernelGGL(k_transpose_x, dim3((Tx * INx * Bx + 255) / 256), dim3(256), 0, stream, x, xT);
    hipLaunchKernelGGL(k_transpose_oh, dim3((Ux * Vx * Bx + 255) / 256), dim3(256), 0, stream, oneh, ohT);
    hipLaunchKernelGGL(k_packW, dim3((200 * 1200 + 255) / 256), dim3(256), 0, stream, Whh0, Wpk0);
    hipLaunchKernelGGL(k_packW, dim3((200 * 1200 + 255) / 256), dim3(256), 0, stream, Whh1, Wpk12);

    // Layer 0: single sync-free persistent launch over all 800 steps
    hipLaunchKernelGGL((k_rec<1>), dim3(16), dim3(640), 0, stream,
                       Wpk0, (const float*)nullptr, xT, h0i, Wih0, bih0, bhh0,
                       out0, 0, Tx);

    hipLaunchKernelGGL(k_abk, dim3(Tx), dim3(256), 0, stream, out0, Wwin, bwin, abk);
    hipLaunchKernelGGL(k_cumsum, dim3(10), dim3(64), 0, stream, abk);
    hipLaunchKernelGGL(k_window, dim3(Tx), dim3(256), 0, stream, abk, ohT, winb);

    // Layer 1: chunked xg + sync-free recurrence
    for (int c = 0; c < NC; c++) {
        hipLaunchKernelGGL(k_xg, dim3(TT, 75), dim3(256), 0, stream,
                           out0, winb, xT, Wih1, bih1, xg, c * TT);
        hipLaunchKernelGGL((k_rec<0>), dim3(16), dim3(640), 0, stream,
                           Wpk12, xg, xT, h1i, (const float*)nullptr, bih1, bhh1,
                           out12, c * TT, TT);
    }
    // Layer 2 (same weights), output reuses out0
    for (int c = 0; c < NC; c++) {
        hipLaunchKernelGGL(k_xg, dim3(TT, 75), dim3(256), 0, stream,
                           out12, winb, xT, Wih1, bih1, xg, c * TT);
        hipLaunchKernelGGL((k_rec<0>), dim3(16), dim3(640), 0, stream,
                           Wpk12, xg, xT, h2i, (const float*)nullptr, bih1, bhh1,
                           out0, c * TT, TT);
    }
    hipLaunchKernelGGL(k_mdn, dim3(Tx), dim3(256), 0, stream, out0, Wmdn, bmdn, (float*)d_out);
}